// Round 1
// baseline (9772.334 us; speedup 1.0000x reference)
//
#include <hip/hip_runtime.h>
#include <math.h>

#define T_LEN 32512
#define BATCH 2
#define NMEL 80
#define FRAMES 128
#define RCH 64
#define SCH 128
#define NCH 256
#define UPK 512
#define NBLK 30

// ---- workspace layout (float offsets) ----
// During block loop: cond, res0, res1, wdilT, wcondT live in [0, 14.3M).
// y1 (post1 output) aliases [0, 16.6M) -- cond/res dead by then.
// skip and p2T live beyond 16.6M floats.
#define COND_OFF   0u
#define RES0_OFF   5201920u
#define RES1_OFF   9363456u
#define WDILT_OFF  13524992u
#define WCONDT_OFF 14016512u
#define Y1_OFF     0u
#define SKIP_OFF   16646144u
#define P2T_OFF    24969216u
// total floats needed: 25034752  (~100.1 MB)

static __device__ __forceinline__ float sigmoidf_(float x) {
  return 1.f / (1.f + __expf(-x));
}
static __device__ __forceinline__ float tanhf_(float x) {
  return 2.f / (1.f + __expf(-2.f * x)) - 1.f;
}

// Transpose weights for contiguous inner-o access.
__global__ __launch_bounds__(256) void prep_kernel(
    const float* __restrict__ dil_w, const float* __restrict__ cond_w,
    const float* __restrict__ p2_w,
    float* __restrict__ wdilT, float* __restrict__ wcondT,
    float* __restrict__ p2T) {
  int tid = blockIdx.x * blockDim.x + threadIdx.x;
  int stride = gridDim.x * blockDim.x;
  // dil: [i][o][ci][k] -> [i][ci][k][o]
  for (int idx = tid; idx < NBLK * 128 * 64 * 2; idx += stride) {
    int k = idx & 1, ci = (idx >> 1) & 63, o = (idx >> 7) & 127, i = idx >> 14;
    wdilT[(((i * 64) + ci) * 2 + k) * 128 + o] = dil_w[idx];
  }
  // cond: [i][o][ci] -> [i][ci][o]
  for (int idx = tid; idx < NBLK * 128 * 80; idx += stride) {
    int ci = idx % 80; int rest = idx / 80; int o = rest & 127; int i = rest >> 7;
    wcondT[((i * 80) + ci) * 128 + o] = cond_w[idx];
  }
  // post2: [oc][ic] -> [ic][oc]
  for (int idx = tid; idx < 256 * 256; idx += stride) {
    int ic = idx & 255, oc = idx >> 8;
    p2T[ic * 256 + oc] = p2_w[idx];
  }
}

// Transposed-conv upsample of mels. For t = 256*M + u (u in [0,256)):
// cond[b,c,t] = b[c] + sum_ci w[c,ci,255-u]*mels[b,ci,M] + w[c,ci,511-u]*mels[b,ci,M+1]
// Each block: 4 consecutive M (j=0..3), 20 output channels, reusing weight loads 4x.
__global__ __launch_bounds__(256) void cond_kernel(
    const float* __restrict__ mels, const float* __restrict__ mel_w,
    const float* __restrict__ mel_b, float* __restrict__ cond) {
  const int u = threadIdx.x;
  const int g = blockIdx.x;   // M-group: M = 4g + j
  const int cc = blockIdx.y;  // channel chunk of 20
  const int b = blockIdx.z;
  const int k0 = 255 - u;
  const int M0 = g * 4;
  const float* melb = mels + (size_t)b * NMEL * FRAMES;
  const bool m4ok = (M0 + 4) < FRAMES;
  for (int c = cc * 20; c < cc * 20 + 20; ++c) {
    float acc0 = 0.f, acc1 = 0.f, acc2 = 0.f, acc3 = 0.f;
    const float* wrow = mel_w + ((size_t)c * NMEL) * UPK + k0;
    for (int ci = 0; ci < NMEL; ++ci) {
      float w0 = wrow[(size_t)ci * UPK];
      float w1 = wrow[(size_t)ci * UPK + 256];
      const float* ml = melb + (size_t)ci * FRAMES + M0;
      float m0 = ml[0], m1 = ml[1], m2 = ml[2], m3 = ml[3];
      float m4 = m4ok ? ml[4] : 0.f;
      acc0 += w0 * m0 + w1 * m1;
      acc1 += w0 * m1 + w1 * m2;
      acc2 += w0 * m2 + w1 * m3;
      acc3 += w0 * m3 + w1 * m4;
    }
    float bv = mel_b[c];
    float* cb = cond + ((size_t)b * NMEL + c) * T_LEN;
    // valid M range is [0,127): t = 256*M + u
    if (M0 + 0 < 127) cb[(M0 + 0) * 256 + u] = acc0 + bv;
    if (M0 + 1 < 127) cb[(M0 + 1) * 256 + u] = acc1 + bv;
    if (M0 + 2 < 127) cb[(M0 + 2) * 256 + u] = acc2 + bv;
    if (M0 + 3 < 127) cb[(M0 + 3) * 256 + u] = acc3 + bv;
  }
}

// res0[b,c,t] = x[b,t]*input_w[c] + input_b[c]
__global__ __launch_bounds__(256) void init_res_kernel(
    const float* __restrict__ x, const float* __restrict__ iw,
    const float* __restrict__ ib, float* __restrict__ res) {
  int idx = blockIdx.x * blockDim.x + threadIdx.x;
  if (idx >= BATCH * RCH * T_LEN) return;
  int t = idx % T_LEN;
  int c = (idx / T_LEN) % RCH;
  int b = idx / (T_LEN * RCH);
  res[idx] = x[(size_t)b * T_LEN + t] * iw[c] + ib[c];
}

// One WaveNet residual block. One lane per time position, z[128] in registers.
__global__ __launch_bounds__(64) void wn_block_kernel(
    const float* __restrict__ res_in, float* __restrict__ res_out,
    const float* __restrict__ cond, float* __restrict__ skip,
    const float* __restrict__ wdilT, const float* __restrict__ wcondT,
    const float* __restrict__ wskip, const float* __restrict__ wres,
    const float* __restrict__ dil_b, const float* __restrict__ cond_b,
    const float* __restrict__ skip_b, const float* __restrict__ res_b,
    int blk, int dil) {
  const int t = blockIdx.x * 64 + threadIdx.x;
  const int b = blockIdx.y;
  float z[128];
  {
    const float* db = dil_b + blk * 128;
    const float* cb = cond_b + blk * 128;
    #pragma unroll
    for (int o = 0; o < 128; ++o) z[o] = db[o] + cb[o];
  }
  const float* rbase = res_in + (size_t)b * RCH * T_LEN;
  {
    const float* wd = wdilT + (size_t)blk * (RCH * 2 * 128);
    const int tm = t - dil;
    for (int ci = 0; ci < RCH; ++ci) {
      float r0 = (tm >= 0) ? rbase[(size_t)ci * T_LEN + tm] : 0.f;
      float r1 = rbase[(size_t)ci * T_LEN + t];
      const float4* w0 = (const float4*)(wd + ci * 256);
      const float4* w1 = (const float4*)(wd + ci * 256 + 128);
      #pragma unroll
      for (int q = 0; q < 32; ++q) {
        float4 a = w0[q], c4 = w1[q];
        z[4 * q + 0] += a.x * r0 + c4.x * r1;
        z[4 * q + 1] += a.y * r0 + c4.y * r1;
        z[4 * q + 2] += a.z * r0 + c4.z * r1;
        z[4 * q + 3] += a.w * r0 + c4.w * r1;
      }
    }
  }
  {
    const float* cbase = cond + ((size_t)b * NMEL) * T_LEN + t;
    const float* wc = wcondT + (size_t)blk * (NMEL * 128);
    for (int ci = 0; ci < NMEL; ++ci) {
      float cv = cbase[(size_t)ci * T_LEN];
      const float4* w0 = (const float4*)(wc + ci * 128);
      #pragma unroll
      for (int q = 0; q < 32; ++q) {
        float4 a = w0[q];
        z[4 * q + 0] += a.x * cv;
        z[4 * q + 1] += a.y * cv;
        z[4 * q + 2] += a.z * cv;
        z[4 * q + 3] += a.w * cv;
      }
    }
  }
  float h[64];
  #pragma unroll
  for (int o = 0; o < 64; ++o) {
    h[o] = tanhf_(z[o]) * sigmoidf_(z[o + 64]);
  }
  {
    const float* wsk = wskip + (size_t)blk * (SCH * RCH);
    const float* sb = skip_b + blk * SCH;
    float* sbase = skip + ((size_t)b * SCH) * T_LEN + t;
    for (int so = 0; so < SCH; ++so) {
      float acc = sb[so];
      const float4* w0 = (const float4*)(wsk + so * RCH);
      #pragma unroll
      for (int q = 0; q < 16; ++q) {
        float4 a = w0[q];
        acc += a.x * h[4 * q] + a.y * h[4 * q + 1] + a.z * h[4 * q + 2] +
               a.w * h[4 * q + 3];
      }
      sbase[(size_t)so * T_LEN] += acc;
    }
  }
  {
    const float* wr = wres + (size_t)blk * (RCH * RCH);
    const float* rb = res_b + blk * RCH;
    const float* rin = rbase + t;
    float* rout = res_out + ((size_t)b * RCH) * T_LEN + t;
    for (int ro = 0; ro < RCH; ++ro) {
      float acc = rb[ro];
      const float4* w0 = (const float4*)(wr + ro * RCH);
      #pragma unroll
      for (int q = 0; q < 16; ++q) {
        float4 a = w0[q];
        acc += a.x * h[4 * q] + a.y * h[4 * q + 1] + a.z * h[4 * q + 2] +
               a.w * h[4 * q + 3];
      }
      rout[(size_t)ro * T_LEN] = rin[(size_t)ro * T_LEN] + acc;
    }
  }
}

// y1 = post1_w @ relu(skip) + b ; input row staged in registers.
__global__ __launch_bounds__(64) void post1_kernel(
    const float* __restrict__ skip, const float* __restrict__ w,
    const float* __restrict__ bias, float* __restrict__ y1) {
  const int t = blockIdx.x * 64 + threadIdx.x;
  const int b = blockIdx.y;
  const float* sbase = skip + ((size_t)b * SCH) * T_LEN + t;
  float in[SCH];
  #pragma unroll
  for (int ic = 0; ic < SCH; ++ic) in[ic] = fmaxf(sbase[(size_t)ic * T_LEN], 0.f);
  float* ybase = y1 + ((size_t)b * NCH) * T_LEN + t;
  for (int oc = 0; oc < NCH; ++oc) {
    float acc = bias[oc];
    const float4* w0 = (const float4*)(w + (size_t)oc * SCH);
    #pragma unroll
    for (int q = 0; q < SCH / 4; ++q) {
      float4 a = w0[q];
      acc += a.x * in[4 * q] + a.y * in[4 * q + 1] + a.z * in[4 * q + 2] +
             a.w * in[4 * q + 3];
    }
    ybase[(size_t)oc * T_LEN] = acc;
  }
}

// out = post2_w @ relu(y1) + b ; chunked accumulators, transposed weights.
__global__ __launch_bounds__(64) void post2_kernel(
    const float* __restrict__ y1, const float* __restrict__ wT,
    const float* __restrict__ bias, float* __restrict__ out) {
  const int t = blockIdx.x * 64 + threadIdx.x;
  const int b = blockIdx.y;
  const float* ybase = y1 + ((size_t)b * NCH) * T_LEN + t;
  float* obase = out + ((size_t)b * NCH) * T_LEN + t;
  for (int ocb = 0; ocb < 4; ++ocb) {
    float acc[64];
    #pragma unroll
    for (int j = 0; j < 64; ++j) acc[j] = bias[ocb * 64 + j];
    for (int ic = 0; ic < NCH; ++ic) {
      float v = fmaxf(ybase[(size_t)ic * T_LEN], 0.f);
      const float4* w0 = (const float4*)(wT + (size_t)ic * NCH + ocb * 64);
      #pragma unroll
      for (int q = 0; q < 16; ++q) {
        float4 a = w0[q];
        acc[4 * q + 0] += a.x * v;
        acc[4 * q + 1] += a.y * v;
        acc[4 * q + 2] += a.z * v;
        acc[4 * q + 3] += a.w * v;
      }
    }
    #pragma unroll
    for (int j = 0; j < 64; ++j) obase[(size_t)(ocb * 64 + j) * T_LEN] = acc[j];
  }
}

extern "C" void kernel_launch(void* const* d_in, const int* in_sizes, int n_in,
                              void* d_out, int out_size, void* d_ws,
                              size_t ws_size, hipStream_t stream) {
  const float* x       = (const float*)d_in[0];
  const float* mels    = (const float*)d_in[1];
  const float* input_w = (const float*)d_in[2];
  const float* input_b = (const float*)d_in[3];
  const float* mel_w   = (const float*)d_in[4];
  const float* mel_b   = (const float*)d_in[5];
  const float* dil_w   = (const float*)d_in[6];
  const float* dil_b   = (const float*)d_in[7];
  const float* cond_w  = (const float*)d_in[8];
  const float* cond_b  = (const float*)d_in[9];
  const float* skip_w  = (const float*)d_in[10];
  const float* skip_b  = (const float*)d_in[11];
  const float* res_w   = (const float*)d_in[12];
  const float* res_b   = (const float*)d_in[13];
  const float* p1_w    = (const float*)d_in[14];
  const float* p1_b    = (const float*)d_in[15];
  const float* p2_w    = (const float*)d_in[16];
  const float* p2_b    = (const float*)d_in[17];

  float* ws = (float*)d_ws;
  float* out = (float*)d_out;

  float* cond   = ws + COND_OFF;
  float* res0   = ws + RES0_OFF;
  float* res1   = ws + RES1_OFF;
  float* wdilT  = ws + WDILT_OFF;
  float* wcondT = ws + WCONDT_OFF;
  float* y1     = ws + Y1_OFF;
  float* skip   = ws + SKIP_OFF;
  float* p2T    = ws + P2T_OFF;

  prep_kernel<<<128, 256, 0, stream>>>(dil_w, cond_w, p2_w, wdilT, wcondT, p2T);
  cond_kernel<<<dim3(32, 4, BATCH), 256, 0, stream>>>(mels, mel_w, mel_b, cond);
  init_res_kernel<<<(BATCH * RCH * T_LEN + 255) / 256, 256, 0, stream>>>(
      x, input_w, input_b, res0);
  hipMemsetAsync(skip, 0, (size_t)BATCH * SCH * T_LEN * sizeof(float), stream);

  float* rin = res0;
  float* rout = res1;
  for (int i = 0; i < NBLK; ++i) {
    int d = 1 << (i % 10);
    wn_block_kernel<<<dim3(T_LEN / 64, BATCH), 64, 0, stream>>>(
        rin, rout, cond, skip, wdilT, wcondT, skip_w, res_w, dil_b, cond_b,
        skip_b, res_b, i, d);
    float* tmp = rin; rin = rout; rout = tmp;
  }

  post1_kernel<<<dim3(T_LEN / 64, BATCH), 64, 0, stream>>>(skip, p1_w, p1_b, y1);
  post2_kernel<<<dim3(T_LEN / 64, BATCH), 64, 0, stream>>>(y1, p2T, p2_b, out);
}

// Round 2
// 1221.692 us; speedup vs baseline: 7.9990x; 7.9990x over previous
//
#include <hip/hip_runtime.h>
#include <math.h>

#define T_LEN 32512
#define BATCH 2
#define NMEL 80
#define FRAMES 128
#define NBLK 30

typedef short bfrag __attribute__((ext_vector_type(8)));
typedef float facc __attribute__((ext_vector_type(4)));
typedef ushort us4v __attribute__((ext_vector_type(4)));
typedef ushort us8v __attribute__((ext_vector_type(8)));

#define MFMA16(a, b, c) __builtin_amdgcn_mfma_f32_16x16x32_bf16((a), (b), (c), 0, 0, 0)

// ---- workspace layout (byte offsets) ----
#define RES0_OFF 0u                  // fp32 [2][64][T]   16,646,144 B
#define RES1_OFF 16646144u           // fp32 [2][64][T]
#define SKIP_OFF 33292288u           // fp32 [2][128][T]  33,292,288 B
#define COND_OFF 66584576u           // bf16 [2][80][T]   10,403,840 B
#define WA_OFF   76988416u           // bf16 frags 30*56*512
#define WSF_OFF  78708736u           // bf16 frags 30*16*512
#define WRF_OFF  79200256u           // bf16 frags 30*8*512
#define WP1_OFF  79446016u           // bf16 frags 64*512
#define WP2_OFF  79511552u           // bf16 frags 128*512
#define Y1R_OFF  0u                  // bf16 [2][256][T] aliases RES0+RES1 (dead)
// total: 79,642,624 B

static __device__ __forceinline__ ushort f2bf(float f) {
  union { float f; unsigned int u; } v;
  v.f = f;
  unsigned int r = (v.u + 0x7FFFu + ((v.u >> 16) & 1u)) >> 16;
  return (ushort)r;
}
static __device__ __forceinline__ float sigmoidf_(float x) {
  return 1.f / (1.f + __expf(-x));
}
static __device__ __forceinline__ float tanhf_(float x) {
  return 2.f / (1.f + __expf(-2.f * x)) - 1.f;
}
static __device__ __forceinline__ bfrag ldfrag(const ushort* p) {
  return *reinterpret_cast<const bfrag*>(p);
}

// ---- prep: swizzle all weights into MFMA A-fragment-major bf16 ----
// Fragment = 512 bf16: lane*8+j, value = W[m=16*mt+(lane&15)][k=32*kt+8*(lane>>4)+j]
__global__ __launch_bounds__(256) void prep_kernel(
    const float* __restrict__ dil_w, const float* __restrict__ cond_w,
    const float* __restrict__ skip_w, const float* __restrict__ res_w,
    const float* __restrict__ p1_w, const float* __restrict__ p2_w,
    ushort* __restrict__ wa, ushort* __restrict__ wsf, ushort* __restrict__ wrf,
    ushort* __restrict__ wp1, ushort* __restrict__ wp2) {
  int tid = blockIdx.x * blockDim.x + threadIdx.x;
  int stride = gridDim.x * blockDim.x;
  // W_all[layer][128 m][224 k] : k<64 dil tap0 (res[t-d]); k<128 dil tap1 (res[t]);
  // k<208 cond; else 0.  frag f = mt*7+kt.
  for (int idx = tid; idx < NBLK * 56 * 512; idx += stride) {
    int j = idx & 7, lane = (idx >> 3) & 63;
    int f = (idx >> 9) % 56, layer = idx / (56 * 512);
    int mt = f / 7, kt = f % 7;
    int m = 16 * mt + (lane & 15);
    int k = 32 * kt + 8 * (lane >> 4) + j;
    float v;
    if (k < 64)       v = dil_w[(((size_t)layer * 128 + m) * 64 + k) * 2 + 0];
    else if (k < 128) v = dil_w[(((size_t)layer * 128 + m) * 64 + (k - 64)) * 2 + 1];
    else if (k < 208) v = cond_w[((size_t)layer * 128 + m) * 80 + (k - 128)];
    else              v = 0.f;
    wa[idx] = f2bf(v);
  }
  // skip W [128 m][64 k], f = mt*2+kt
  for (int idx = tid; idx < NBLK * 16 * 512; idx += stride) {
    int j = idx & 7, lane = (idx >> 3) & 63;
    int f = (idx >> 9) & 15, layer = idx / (16 * 512);
    int mt = f >> 1, kt = f & 1;
    int m = 16 * mt + (lane & 15);
    int k = 32 * kt + 8 * (lane >> 4) + j;
    wsf[idx] = f2bf(skip_w[((size_t)layer * 128 + m) * 64 + k]);
  }
  // res W [64 m][64 k], f = mt*2+kt
  for (int idx = tid; idx < NBLK * 8 * 512; idx += stride) {
    int j = idx & 7, lane = (idx >> 3) & 63;
    int f = (idx >> 9) & 7, layer = idx / (8 * 512);
    int mt = f >> 1, kt = f & 1;
    int m = 16 * mt + (lane & 15);
    int k = 32 * kt + 8 * (lane >> 4) + j;
    wrf[idx] = f2bf(res_w[((size_t)layer * 64 + m) * 64 + k]);
  }
  // post1 W [256 m][128 k], f = mt*4+kt
  for (int idx = tid; idx < 64 * 512; idx += stride) {
    int j = idx & 7, lane = (idx >> 3) & 63;
    int f = idx >> 9;
    int mt = f >> 2, kt = f & 3;
    int m = 16 * mt + (lane & 15);
    int k = 32 * kt + 8 * (lane >> 4) + j;
    wp1[idx] = f2bf(p1_w[(size_t)m * 128 + k]);
  }
  // post2 W [256 m][256 k], f = mt*8+kt
  for (int idx = tid; idx < 128 * 512; idx += stride) {
    int j = idx & 7, lane = (idx >> 3) & 63;
    int f = idx >> 9;
    int mt = f >> 3, kt = f & 7;
    int m = 16 * mt + (lane & 15);
    int k = 32 * kt + 8 * (lane >> 4) + j;
    wp2[idx] = f2bf(p2_w[(size_t)m * 256 + k]);
  }
}

// ---- mel upsample (unchanged math, bf16 output) ----
__global__ __launch_bounds__(256) void cond_kernel(
    const float* __restrict__ mels, const float* __restrict__ mel_w,
    const float* __restrict__ mel_b, ushort* __restrict__ cond) {
  const int u = threadIdx.x;
  const int g = blockIdx.x;
  const int cc = blockIdx.y;
  const int b = blockIdx.z;
  const int k0 = 255 - u;
  const int M0 = g * 4;
  const float* melb = mels + (size_t)b * NMEL * FRAMES;
  const bool m4ok = (M0 + 4) < FRAMES;
  for (int c = cc * 20; c < cc * 20 + 20; ++c) {
    float acc0 = 0.f, acc1 = 0.f, acc2 = 0.f, acc3 = 0.f;
    const float* wrow = mel_w + ((size_t)c * NMEL) * 512 + k0;
    for (int ci = 0; ci < NMEL; ++ci) {
      float w0 = wrow[(size_t)ci * 512];
      float w1 = wrow[(size_t)ci * 512 + 256];
      const float* ml = melb + (size_t)ci * FRAMES + M0;
      float m0 = ml[0], m1 = ml[1], m2 = ml[2], m3 = ml[3];
      float m4 = m4ok ? ml[4] : 0.f;
      acc0 += w0 * m0 + w1 * m1;
      acc1 += w0 * m1 + w1 * m2;
      acc2 += w0 * m2 + w1 * m3;
      acc3 += w0 * m3 + w1 * m4;
    }
    float bv = mel_b[c];
    ushort* cb = cond + ((size_t)b * NMEL + c) * T_LEN;
    if (M0 + 0 < 127) cb[(M0 + 0) * 256 + u] = f2bf(acc0 + bv);
    if (M0 + 1 < 127) cb[(M0 + 1) * 256 + u] = f2bf(acc1 + bv);
    if (M0 + 2 < 127) cb[(M0 + 2) * 256 + u] = f2bf(acc2 + bv);
    if (M0 + 3 < 127) cb[(M0 + 3) * 256 + u] = f2bf(acc3 + bv);
  }
}

__global__ __launch_bounds__(256) void init_res_kernel(
    const float* __restrict__ x, const float* __restrict__ iw,
    const float* __restrict__ ib, float* __restrict__ res) {
  int idx = blockIdx.x * blockDim.x + threadIdx.x;
  if (idx >= BATCH * 64 * T_LEN) return;
  int t = idx % T_LEN;
  int c = (idx / T_LEN) % 64;
  int b = idx / (T_LEN * 64);
  res[idx] = x[(size_t)b * T_LEN + t] * iw[c] + ib[c];
}

// ---- one residual block, MFMA. 256 thr = 4 waves, tile = 64 time positions.
#define XSTR 232
#define HSTR 72
__global__ __launch_bounds__(256) void wn_mfma_kernel(
    const float* __restrict__ res_in, float* __restrict__ res_out,
    const ushort* __restrict__ cond, float* __restrict__ skip,
    const ushort* __restrict__ wa, const ushort* __restrict__ wsf,
    const ushort* __restrict__ wrf,
    const float* __restrict__ dil_b, const float* __restrict__ cond_b,
    const float* __restrict__ skip_b, const float* __restrict__ res_b,
    int blk, int dil) {
  __shared__ ushort XT[64 * XSTR];  // X^T[t][k], k: 224 (padded rows 208-223 = 0)
  __shared__ ushort HT[64 * HSTR];  // h^T[t][ch], ch: 64
  const int tid = threadIdx.x;
  const int lane = tid & 63;
  const int w = tid >> 6;
  const int t0 = blockIdx.x * 64;
  const int b = blockIdx.y;

  const float* rb = res_in + (size_t)b * 64 * T_LEN;
  const ushort* cb = cond + (size_t)b * NMEL * T_LEN;

  // build X^T
  {
    const int t = t0 + lane;
    const int tm = t - dil;
    for (int kc = 0; kc < 7; ++kc) {
      const int k0 = w * 56 + kc * 8;
      us8v v;
      if (k0 < 64) {
        #pragma unroll
        for (int j = 0; j < 8; ++j) {
          float f = (tm >= 0) ? rb[(size_t)(k0 + j) * T_LEN + tm] : 0.f;
          v[j] = f2bf(f);
        }
      } else if (k0 < 128) {
        #pragma unroll
        for (int j = 0; j < 8; ++j) v[j] = f2bf(rb[(size_t)(k0 - 64 + j) * T_LEN + t]);
      } else if (k0 < 208) {
        #pragma unroll
        for (int j = 0; j < 8; ++j) v[j] = cb[(size_t)(k0 - 128 + j) * T_LEN + t];
      } else {
        #pragma unroll
        for (int j = 0; j < 8; ++j) v[j] = 0;
      }
      *reinterpret_cast<us8v*>(&XT[lane * XSTR + k0]) = v;
    }
  }
  __syncthreads();

  // phase A: z[128][64] = W_all @ X  (wave w owns m-tiles w (f) and w+4 (g))
  facc accF[4], accG[4];
  {
    const int q4 = 4 * (lane >> 4);
    facc bF, bG;
    #pragma unroll
    for (int r = 0; r < 4; ++r) {
      int mF = blk * 128 + 16 * w + q4 + r;
      bF[r] = dil_b[mF] + cond_b[mF];
      bG[r] = dil_b[mF + 64] + cond_b[mF + 64];
    }
    #pragma unroll
    for (int nt = 0; nt < 4; ++nt) { accF[nt] = bF; accG[nt] = bG; }
  }
  {
    const ushort* wal = wa + (size_t)blk * 56 * 512;
    const int lo = lane * 8;
    const int bofs = (lane & 15) * XSTR + 8 * (lane >> 4);
    #pragma unroll
    for (int kt = 0; kt < 7; ++kt) {
      bfrag aF = ldfrag(wal + (w * 7 + kt) * 512 + lo);
      bfrag aG = ldfrag(wal + ((w + 4) * 7 + kt) * 512 + lo);
      #pragma unroll
      for (int nt = 0; nt < 4; ++nt) {
        bfrag bb = ldfrag(&XT[nt * 16 * XSTR + bofs + kt * 32]);
        accF[nt] = MFMA16(aF, bb, accF[nt]);
        accG[nt] = MFMA16(aG, bb, accG[nt]);
      }
    }
  }

  // gate -> HT[t][ch] bf16
  {
    const int ch = 16 * w + 4 * (lane >> 4);
    #pragma unroll
    for (int nt = 0; nt < 4; ++nt) {
      us4v p;
      #pragma unroll
      for (int r = 0; r < 4; ++r) {
        float h = tanhf_(accF[nt][r]) * sigmoidf_(accG[nt][r]);
        p[r] = f2bf(h);
      }
      const int tloc = nt * 16 + (lane & 15);
      *reinterpret_cast<us4v*>(&HT[tloc * HSTR + ch]) = p;
    }
  }
  __syncthreads();

  // phases C+D: skip += Ws@h ; res_out = res_in + Wr@h
  facc accS0[4], accS1[4], accR[4];
  {
    const int q4 = 4 * (lane >> 4);
    facc b0, b1, br;
    #pragma unroll
    for (int r = 0; r < 4; ++r) {
      b0[r] = skip_b[blk * 128 + 32 * w + q4 + r];
      b1[r] = skip_b[blk * 128 + 32 * w + 16 + q4 + r];
      br[r] = res_b[blk * 64 + 16 * w + q4 + r];
    }
    #pragma unroll
    for (int nt = 0; nt < 4; ++nt) { accS0[nt] = b0; accS1[nt] = b1; accR[nt] = br; }
  }
  {
    const ushort* wsl = wsf + (size_t)blk * 16 * 512;
    const ushort* wrl = wrf + (size_t)blk * 8 * 512;
    const int lo = lane * 8;
    const int bofs = (lane & 15) * HSTR + 8 * (lane >> 4);
    #pragma unroll
    for (int kt = 0; kt < 2; ++kt) {
      bfrag a0 = ldfrag(wsl + ((2 * w) * 2 + kt) * 512 + lo);
      bfrag a1 = ldfrag(wsl + ((2 * w + 1) * 2 + kt) * 512 + lo);
      bfrag ar = ldfrag(wrl + (w * 2 + kt) * 512 + lo);
      #pragma unroll
      for (int nt = 0; nt < 4; ++nt) {
        bfrag bb = ldfrag(&HT[nt * 16 * HSTR + bofs + kt * 32]);
        accS0[nt] = MFMA16(a0, bb, accS0[nt]);
        accS1[nt] = MFMA16(a1, bb, accS1[nt]);
        accR[nt]  = MFMA16(ar, bb, accR[nt]);
      }
    }
  }
  {
    float* sg = skip + (size_t)b * 128 * T_LEN;
    float* ro = res_out + (size_t)b * 64 * T_LEN;
    const int q4 = 4 * (lane >> 4);
    #pragma unroll
    for (int nt = 0; nt < 4; ++nt) {
      const int tt = t0 + nt * 16 + (lane & 15);
      #pragma unroll
      for (int r = 0; r < 4; ++r) {
        sg[(size_t)(32 * w + q4 + r) * T_LEN + tt] += accS0[nt][r];
        sg[(size_t)(32 * w + 16 + q4 + r) * T_LEN + tt] += accS1[nt][r];
        float rv = rb[(size_t)(16 * w + q4 + r) * T_LEN + tt];
        ro[(size_t)(16 * w + q4 + r) * T_LEN + tt] = rv + accR[nt][r];
      }
    }
  }
}

// ---- post1: y1r = bf16(relu(p1_w @ relu(skip) + b)) ----
#define SSTR 136
__global__ __launch_bounds__(256) void post1_mfma(
    const float* __restrict__ skip, const ushort* __restrict__ wp1,
    const float* __restrict__ p1b, ushort* __restrict__ y1r) {
  __shared__ ushort ST[64 * SSTR];
  const int tid = threadIdx.x;
  const int lane = tid & 63;
  const int w = tid >> 6;
  const int t0 = blockIdx.x * 64;
  const int b = blockIdx.y;
  const float* sb = skip + (size_t)b * 128 * T_LEN;
  const int t = t0 + lane;
  for (int kc = 0; kc < 4; ++kc) {
    int k0 = w * 32 + kc * 8;
    us8v v;
    #pragma unroll
    for (int j = 0; j < 8; ++j)
      v[j] = f2bf(fmaxf(sb[(size_t)(k0 + j) * T_LEN + t], 0.f));
    *reinterpret_cast<us8v*>(&ST[lane * SSTR + k0]) = v;
  }
  __syncthreads();
  const int q4 = 4 * (lane >> 4);
  facc acc[4][4];
  #pragma unroll
  for (int mi = 0; mi < 4; ++mi) {
    facc bi;
    #pragma unroll
    for (int r = 0; r < 4; ++r) bi[r] = p1b[16 * (4 * w + mi) + q4 + r];
    #pragma unroll
    for (int nt = 0; nt < 4; ++nt) acc[mi][nt] = bi;
  }
  const int lo = lane * 8;
  const int bofs = (lane & 15) * SSTR + 8 * (lane >> 4);
  #pragma unroll
  for (int kt = 0; kt < 4; ++kt) {
    bfrag a[4];
    #pragma unroll
    for (int mi = 0; mi < 4; ++mi)
      a[mi] = ldfrag(wp1 + ((4 * w + mi) * 4 + kt) * 512 + lo);
    #pragma unroll
    for (int nt = 0; nt < 4; ++nt) {
      bfrag bb = ldfrag(&ST[nt * 16 * SSTR + bofs + kt * 32]);
      #pragma unroll
      for (int mi = 0; mi < 4; ++mi) acc[mi][nt] = MFMA16(a[mi], bb, acc[mi][nt]);
    }
  }
  ushort* yb = y1r + (size_t)b * 256 * T_LEN;
  #pragma unroll
  for (int mi = 0; mi < 4; ++mi) {
    #pragma unroll
    for (int nt = 0; nt < 4; ++nt) {
      const int tt = t0 + nt * 16 + (lane & 15);
      #pragma unroll
      for (int r = 0; r < 4; ++r)
        yb[(size_t)(16 * (4 * w + mi) + q4 + r) * T_LEN + tt] =
            f2bf(fmaxf(acc[mi][nt][r], 0.f));
    }
  }
}

// ---- post2: out = p2_w @ y1r + b (fp32 out) ----
#define YSTR 264
__global__ __launch_bounds__(256) void post2_mfma(
    const ushort* __restrict__ y1r, const ushort* __restrict__ wp2,
    const float* __restrict__ p2b, float* __restrict__ out) {
  __shared__ ushort YT[64 * YSTR];
  const int tid = threadIdx.x;
  const int lane = tid & 63;
  const int w = tid >> 6;
  const int t0 = blockIdx.x * 64;
  const int b = blockIdx.y;
  const ushort* yb = y1r + (size_t)b * 256 * T_LEN;
  const int t = t0 + lane;
  for (int kc = 0; kc < 8; ++kc) {
    int k0 = w * 64 + kc * 8;
    us8v v;
    #pragma unroll
    for (int j = 0; j < 8; ++j) v[j] = yb[(size_t)(k0 + j) * T_LEN + t];
    *reinterpret_cast<us8v*>(&YT[lane * YSTR + k0]) = v;
  }
  __syncthreads();
  const int q4 = 4 * (lane >> 4);
  facc acc[4][4];
  #pragma unroll
  for (int mi = 0; mi < 4; ++mi) {
    facc bi;
    #pragma unroll
    for (int r = 0; r < 4; ++r) bi[r] = p2b[16 * (4 * w + mi) + q4 + r];
    #pragma unroll
    for (int nt = 0; nt < 4; ++nt) acc[mi][nt] = bi;
  }
  const int lo = lane * 8;
  const int bofs = (lane & 15) * YSTR + 8 * (lane >> 4);
  #pragma unroll
  for (int kt = 0; kt < 8; ++kt) {
    bfrag a[4];
    #pragma unroll
    for (int mi = 0; mi < 4; ++mi)
      a[mi] = ldfrag(wp2 + ((4 * w + mi) * 8 + kt) * 512 + lo);
    #pragma unroll
    for (int nt = 0; nt < 4; ++nt) {
      bfrag bb = ldfrag(&YT[nt * 16 * YSTR + bofs + kt * 32]);
      #pragma unroll
      for (int mi = 0; mi < 4; ++mi) acc[mi][nt] = MFMA16(a[mi], bb, acc[mi][nt]);
    }
  }
  float* ob = out + (size_t)b * 256 * T_LEN;
  #pragma unroll
  for (int mi = 0; mi < 4; ++mi) {
    #pragma unroll
    for (int nt = 0; nt < 4; ++nt) {
      const int tt = t0 + nt * 16 + (lane & 15);
      #pragma unroll
      for (int r = 0; r < 4; ++r)
        ob[(size_t)(16 * (4 * w + mi) + q4 + r) * T_LEN + tt] = acc[mi][nt][r];
    }
  }
}

extern "C" void kernel_launch(void* const* d_in, const int* in_sizes, int n_in,
                              void* d_out, int out_size, void* d_ws,
                              size_t ws_size, hipStream_t stream) {
  const float* x       = (const float*)d_in[0];
  const float* mels    = (const float*)d_in[1];
  const float* input_w = (const float*)d_in[2];
  const float* input_b = (const float*)d_in[3];
  const float* mel_w   = (const float*)d_in[4];
  const float* mel_b   = (const float*)d_in[5];
  const float* dil_w   = (const float*)d_in[6];
  const float* dil_b   = (const float*)d_in[7];
  const float* cond_w  = (const float*)d_in[8];
  const float* cond_b  = (const float*)d_in[9];
  const float* skip_w  = (const float*)d_in[10];
  const float* skip_b  = (const float*)d_in[11];
  const float* res_w   = (const float*)d_in[12];
  const float* res_b   = (const float*)d_in[13];
  const float* p1_w    = (const float*)d_in[14];
  const float* p1_b    = (const float*)d_in[15];
  const float* p2_w    = (const float*)d_in[16];
  const float* p2_b    = (const float*)d_in[17];

  char* ws = (char*)d_ws;
  float* res0   = (float*)(ws + RES0_OFF);
  float* res1   = (float*)(ws + RES1_OFF);
  float* skip   = (float*)(ws + SKIP_OFF);
  ushort* cond  = (ushort*)(ws + COND_OFF);
  ushort* wa    = (ushort*)(ws + WA_OFF);
  ushort* wsf   = (ushort*)(ws + WSF_OFF);
  ushort* wrf   = (ushort*)(ws + WRF_OFF);
  ushort* wp1   = (ushort*)(ws + WP1_OFF);
  ushort* wp2   = (ushort*)(ws + WP2_OFF);
  ushort* y1r   = (ushort*)(ws + Y1R_OFF);
  float* out    = (float*)d_out;

  prep_kernel<<<2048, 256, 0, stream>>>(dil_w, cond_w, skip_w, res_w, p1_w,
                                        p2_w, wa, wsf, wrf, wp1, wp2);
  cond_kernel<<<dim3(32, 4, BATCH), 256, 0, stream>>>(mels, mel_w, mel_b, cond);
  init_res_kernel<<<(BATCH * 64 * T_LEN + 255) / 256, 256, 0, stream>>>(
      x, input_w, input_b, res0);
  hipMemsetAsync(skip, 0, (size_t)BATCH * 128 * T_LEN * sizeof(float), stream);

  float* rin = res0;
  float* rout = res1;
  for (int i = 0; i < NBLK; ++i) {
    int d = 1 << (i % 10);
    wn_mfma_kernel<<<dim3(T_LEN / 64, BATCH), 256, 0, stream>>>(
        rin, rout, cond, skip, wa, wsf, wrf, dil_b, cond_b, skip_b, res_b, i, d);
    float* tmp = rin; rin = rout; rout = tmp;
  }

  post1_mfma<<<dim3(T_LEN / 64, BATCH), 256, 0, stream>>>(skip, wp1, p1_b, y1r);
  post2_mfma<<<dim3(T_LEN / 64, BATCH), 256, 0, stream>>>(y1r, wp2, p2_b, out);
}